// Round 2
// baseline (9484.314 us; speedup 1.0000x reference)
//
#include <hip/hip_runtime.h>
#include <hip/hip_bf16.h>
#include <math.h>

#define TOKENS 16384
#define DIM    7168
#define NEXP   256
#define TK     8
#define BM     32
#define BK     32
#define NKT    (DIM / BK)   /* 224 */

// f64-accurate gate: fp32 staging in LDS, f64 convert+FMA in registers,
// f64 logits overlaid on LDS for exact top-8 selection.
__global__ __launch_bounds__(256, 2)
void gate_f64(const float* __restrict__ x,
              const float* __restrict__ w,
              float* __restrict__ outw,
              float* __restrict__ outi)
{
    extern __shared__ __align__(16) char smem[];
    float (*As)[BM + 4]   = (float(*)[BM + 4])smem;            // 32x36 f32 = 4608 B
    float (*Bs)[NEXP + 4] = (float(*)[NEXP + 4])(smem + 4608); // 32x260 f32 = 33280 B
    double (*lgd)[NEXP]   = (double(*)[NEXP])smem;             // 32x256 f64 = 65536 B (overlay)

    const int t    = threadIdx.x;
    const int tx   = t & 31;     // expert coord (0..31) -> experts tx*4+{0..3}, +128
    const int ty   = t >> 5;     // token coord  (0..7)  -> tokens ty*4+{0..3}
    const int lane = t & 63;
    const int wv   = t >> 6;
    const int tok0 = blockIdx.x * BM;

    // staging map: thread loads float4 at (row=ldq, k=kq)
    const int ldq = t >> 3;          // 0..31
    const int kq  = (t & 7) * 4;     // 0,4,...,28

    const float* xp = x + (size_t)(tok0 + ldq) * DIM + kq;
    const float* wp = w + (size_t)ldq * DIM + kq;

    float4 ar, br[8];

    auto load_tile = [&](int kt) {
        ar = *(const float4*)(xp + kt * BK);
        const float* wq = wp + kt * BK;
        #pragma unroll
        for (int i = 0; i < 8; ++i)
            br[i] = *(const float4*)(wq + (size_t)i * 32 * DIM);
    };
    auto stash_tile = [&]() {
        const float* a = (const float*)&ar;
        #pragma unroll
        for (int e = 0; e < 4; ++e)
            As[kq + e][ldq] = a[e];
        #pragma unroll
        for (int i = 0; i < 8; ++i) {
            const float* b = (const float*)&br[i];
            #pragma unroll
            for (int e = 0; e < 4; ++e)
                Bs[kq + e][ldq + i * 32] = b[e];
        }
    };

    double acc[2][4][4];   // [expert-group][token][expert]
    #pragma unroll
    for (int eg = 0; eg < 2; ++eg)
        #pragma unroll
        for (int i = 0; i < 4; ++i)
            #pragma unroll
            for (int j = 0; j < 4; ++j)
                acc[eg][i][j] = 0.0;

    load_tile(0);
    stash_tile();
    __syncthreads();

    for (int kt = 0; kt < NKT; ++kt) {
        if (kt + 1 < NKT) load_tile(kt + 1);   // prefetch hides global latency
        #pragma unroll
        for (int kk = 0; kk < BK; ++kk) {
            float4 a4 = *(const float4*)&As[kk][ty * 4];
            float4 b0 = *(const float4*)&Bs[kk][tx * 4];
            float4 b1 = *(const float4*)&Bs[kk][tx * 4 + 128];
            const float* af = (const float*)&a4;
            const float* b0f = (const float*)&b0;
            const float* b1f = (const float*)&b1;
            double ad[4], bd0[4], bd1[4];
            #pragma unroll
            for (int i = 0; i < 4; ++i) {
                ad[i]  = (double)af[i];
                bd0[i] = (double)b0f[i];
                bd1[i] = (double)b1f[i];
            }
            #pragma unroll
            for (int i = 0; i < 4; ++i)
                #pragma unroll
                for (int j = 0; j < 4; ++j) {
                    acc[0][i][j] = fma(ad[i], bd0[j], acc[0][i][j]);
                    acc[1][i][j] = fma(ad[i], bd1[j], acc[1][i][j]);
                }
        }
        __syncthreads();
        if (kt + 1 < NKT) { stash_tile(); __syncthreads(); }
    }
    // all LDS reads of As/Bs complete and synced; safe to overlay lgd.

    // ---- write f64 logits ----
    #pragma unroll
    for (int eg = 0; eg < 2; ++eg)
        #pragma unroll
        for (int i = 0; i < 4; ++i) {
            double2 d0, d1;
            d0.x = acc[eg][i][0]; d0.y = acc[eg][i][1];
            d1.x = acc[eg][i][2]; d1.y = acc[eg][i][3];
            *(double2*)&lgd[ty * 4 + i][tx * 4 + eg * 128]     = d0;
            *(double2*)&lgd[ty * 4 + i][tx * 4 + eg * 128 + 2] = d1;
        }
    __syncthreads();

    // ---- f64-exact softmax + top-8; each wave owns 8 tokens ----
    for (int r8 = 0; r8 < 8; ++r8) {
        const int row  = wv * 8 + r8;
        const int gtok = tok0 + row;
        double2 v0 = *(const double2*)&lgd[row][lane * 4];
        double2 v1 = *(const double2*)&lgd[row][lane * 4 + 2];
        double vv[4] = {v0.x, v0.y, v1.x, v1.y};

        double m = fmax(fmax(vv[0], vv[1]), fmax(vv[2], vv[3]));
        #pragma unroll
        for (int off = 32; off >= 1; off >>= 1)
            m = fmax(m, __shfl_xor(m, off));

        float s = expf((float)(vv[0] - m)) + expf((float)(vv[1] - m))
                + expf((float)(vv[2] - m)) + expf((float)(vv[3] - m));
        #pragma unroll
        for (int off = 32; off >= 1; off >>= 1)
            s += __shfl_xor(s, off);
        const float invs = 1.0f / s;

        int taken = 0;
        for (int it = 0; it < TK; ++it) {
            double bv = -1.0e300;
            int    bi = 1 << 30;
            #pragma unroll
            for (int j = 0; j < 4; ++j) {
                double cv = ((taken >> j) & 1) ? -1.0e300 : vv[j];
                int    ci = lane * 4 + j;
                if (cv > bv || (cv == bv && ci < bi)) { bv = cv; bi = ci; }
            }
            #pragma unroll
            for (int off = 32; off >= 1; off >>= 1) {
                double ov = __shfl_xor(bv, off);
                int    oi = __shfl_xor(bi, off);
                if (ov > bv || (ov == bv && oi < bi)) { bv = ov; bi = oi; }
            }
            if (lane == it) {
                outw[(size_t)gtok * TK + it] = expf((float)(bv - m)) * invs;
                outi[(size_t)gtok * TK + it] = (float)bi;
            }
            if ((bi >> 2) == lane) taken |= 1 << (bi & 3);
        }
    }
}

extern "C" void kernel_launch(void* const* d_in, const int* in_sizes, int n_in,
                              void* d_out, int out_size, void* d_ws, size_t ws_size,
                              hipStream_t stream) {
    const float* x = (const float*)d_in[0];
    const float* w = (const float*)d_in[1];
    float* outw = (float*)d_out;
    float* outi = outw + (size_t)TOKENS * TK;
    gate_f64<<<dim3(TOKENS / BM), dim3(256), 65536, stream>>>(x, w, outw, outi);
}

// Round 3
// 1499.351 us; speedup vs baseline: 6.3256x; 6.3256x over previous
//
#include <hip/hip_runtime.h>
#include <math.h>

#define TOKENS 16384
#define DIM    7168
#define NEXP   256
#define TK     8
#define BM     32
#define BK     32
#define NKT    (DIM / BK)   /* 224 */

// f32 LDS layout (floats): As[2][32][36] then Bs[2][32][260], double-buffered.
#define AS_OFF(buf)  ((buf) * 1152)
#define BS_OFF(buf)  (2304 + (buf) * 8320)
#define LDS_BYTES    75776
// lgd overlay: 32 x 256 f64 = 65536 B <= 75776

__global__ __launch_bounds__(256, 2)
void gate_f64(const float* __restrict__ x,
              const float* __restrict__ w,
              float* __restrict__ outw,
              float* __restrict__ outi)
{
    extern __shared__ __align__(16) float smemf[];
    double* lgd = (double*)smemf;

    const int t    = threadIdx.x;
    const int tx   = t & 31;     // expert coord: experts tx*4+{0..3} and +128
    const int ty   = t >> 5;     // token coord:  tokens  ty*4+{0..3}
    const int lane = t & 63;
    const int wv   = t >> 6;
    const int tok0 = blockIdx.x * BM;

    // staging map: thread holds row ldq, k-offset kq..kq+3 (float4)
    const int ldq = t >> 3;          // 0..31
    const int kq  = (t & 7) * 4;     // 0,4,...,28

    const float* xp = x + (size_t)(tok0 + ldq) * DIM + kq;
    const float* wp = w + (size_t)ldq * DIM + kq;

    double acc[2][4][4];
    #pragma unroll
    for (int eg = 0; eg < 2; ++eg)
        #pragma unroll
        for (int i = 0; i < 4; ++i)
            #pragma unroll
            for (int j = 0; j < 4; ++j)
                acc[eg][i][j] = 0.0;

    // named staging regs — never address-taken, never in an array
    float4 ar, br0, br1, br2, br3, br4, br5, br6, br7;

#define LOADT(kt) do {                                        \
    const float* xq = xp + (size_t)(kt) * BK;                 \
    ar  = *(const float4*)(xq);                               \
    const float* wq = wp + (size_t)(kt) * BK;                 \
    br0 = *(const float4*)(wq);                               \
    br1 = *(const float4*)(wq + (size_t) 32 * DIM);           \
    br2 = *(const float4*)(wq + (size_t) 64 * DIM);           \
    br3 = *(const float4*)(wq + (size_t) 96 * DIM);           \
    br4 = *(const float4*)(wq + (size_t)128 * DIM);           \
    br5 = *(const float4*)(wq + (size_t)160 * DIM);           \
    br6 = *(const float4*)(wq + (size_t)192 * DIM);           \
    br7 = *(const float4*)(wq + (size_t)224 * DIM);           \
} while (0)

#define STB(Bw, i, v)                                         \
    (Bw)[(kq+0)*260 + ldq + (i)*32] = (v).x;                  \
    (Bw)[(kq+1)*260 + ldq + (i)*32] = (v).y;                  \
    (Bw)[(kq+2)*260 + ldq + (i)*32] = (v).z;                  \
    (Bw)[(kq+3)*260 + ldq + (i)*32] = (v).w;

#define STASH(buf) do {                                       \
    float* Aw = smemf + AS_OFF(buf);                          \
    Aw[(kq+0)*36 + ldq] = ar.x;                               \
    Aw[(kq+1)*36 + ldq] = ar.y;                               \
    Aw[(kq+2)*36 + ldq] = ar.z;                               \
    Aw[(kq+3)*36 + ldq] = ar.w;                               \
    float* Bw = smemf + BS_OFF(buf);                          \
    STB(Bw, 0, br0) STB(Bw, 1, br1) STB(Bw, 2, br2)           \
    STB(Bw, 3, br3) STB(Bw, 4, br4) STB(Bw, 5, br5)           \
    STB(Bw, 6, br6) STB(Bw, 7, br7)                           \
} while (0)

    LOADT(0);
    STASH(0);
    __syncthreads();

    for (int kt = 0; kt < NKT; ++kt) {
        const int cur = kt & 1;
        if (kt + 1 < NKT) LOADT(kt + 1);   // issue early; latency hides under compute
        const float* Ac = smemf + AS_OFF(cur);
        const float* Bc = smemf + BS_OFF(cur);
        #pragma unroll 16
        for (int kk = 0; kk < BK; ++kk) {
            float4 a4 = *(const float4*)(Ac + kk * 36 + ty * 4);
            float4 b0 = *(const float4*)(Bc + kk * 260 + tx * 4);
            float4 b1 = *(const float4*)(Bc + kk * 260 + tx * 4 + 128);
            double ad[4], bd0[4], bd1[4];
            ad[0]  = a4.x; ad[1]  = a4.y; ad[2]  = a4.z; ad[3]  = a4.w;
            bd0[0] = b0.x; bd0[1] = b0.y; bd0[2] = b0.z; bd0[3] = b0.w;
            bd1[0] = b1.x; bd1[1] = b1.y; bd1[2] = b1.z; bd1[3] = b1.w;
            #pragma unroll
            for (int i = 0; i < 4; ++i)
                #pragma unroll
                for (int j = 0; j < 4; ++j) {
                    acc[0][i][j] = fma(ad[i], bd0[j], acc[0][i][j]);
                    acc[1][i][j] = fma(ad[i], bd1[j], acc[1][i][j]);
                }
        }
        if (kt + 1 < NKT) STASH((kt + 1) & 1);
        __syncthreads();
    }

    // ---- write f64 logits into LDS overlay ----
    #pragma unroll
    for (int i = 0; i < 4; ++i) {
        double* lr = lgd + (size_t)(ty * 4 + i) * NEXP + tx * 4;
        lr[0]   = acc[0][i][0]; lr[1]   = acc[0][i][1];
        lr[2]   = acc[0][i][2]; lr[3]   = acc[0][i][3];
        lr[128] = acc[1][i][0]; lr[129] = acc[1][i][1];
        lr[130] = acc[1][i][2]; lr[131] = acc[1][i][3];
    }
    __syncthreads();

    // ---- f64-exact softmax + top-8; each wave owns 8 tokens ----
    for (int r8 = 0; r8 < 8; ++r8) {
        const int row  = wv * 8 + r8;
        const int gtok = tok0 + row;
        const double* lr = lgd + (size_t)row * NEXP + lane * 4;
        double vv[4];
        vv[0] = lr[0]; vv[1] = lr[1]; vv[2] = lr[2]; vv[3] = lr[3];

        double m = fmax(fmax(vv[0], vv[1]), fmax(vv[2], vv[3]));
        #pragma unroll
        for (int off = 32; off >= 1; off >>= 1)
            m = fmax(m, __shfl_xor(m, off));

        float s = expf((float)(vv[0] - m)) + expf((float)(vv[1] - m))
                + expf((float)(vv[2] - m)) + expf((float)(vv[3] - m));
        #pragma unroll
        for (int off = 32; off >= 1; off >>= 1)
            s += __shfl_xor(s, off);
        const float invs = 1.0f / s;

        int taken = 0;
        for (int it = 0; it < TK; ++it) {
            double bv = -1.0e300;
            int    bi = 1 << 30;
            #pragma unroll
            for (int j = 0; j < 4; ++j) {
                double cv = ((taken >> j) & 1) ? -1.0e300 : vv[j];
                int    ci = lane * 4 + j;
                if (cv > bv || (cv == bv && ci < bi)) { bv = cv; bi = ci; }
            }
            #pragma unroll
            for (int off = 32; off >= 1; off >>= 1) {
                double ov = __shfl_xor(bv, off);
                int    oi = __shfl_xor(bi, off);
                if (ov > bv || (ov == bv && oi < bi)) { bv = ov; bi = oi; }
            }
            if (lane == it) {
                outw[(size_t)gtok * TK + it] = expf((float)(bv - m)) * invs;
                outi[(size_t)gtok * TK + it] = (float)bi;
            }
            if ((bi >> 2) == lane) taken |= 1 << (bi & 3);
        }
    }
}

extern "C" void kernel_launch(void* const* d_in, const int* in_sizes, int n_in,
                              void* d_out, int out_size, void* d_ws, size_t ws_size,
                              hipStream_t stream) {
    const float* x = (const float*)d_in[0];
    const float* w = (const float*)d_in[1];
    float* outw = (float*)d_out;
    float* outi = outw + (size_t)TOKENS * TK;
    gate_f64<<<dim3(TOKENS / BM), dim3(256), LDS_BYTES, stream>>>(x, w, outw, outi);
}